// Round 11
// baseline (710.409 us; speedup 1.0000x reference)
//
#include <hip/hip_runtime.h>
#include <math.h>

// B=4, N=256, D=256, H=8, DK=32, DV=32, R=64
constexpr int B_ = 4, N_ = 256, D_ = 256, H_ = 8, DK_ = 32, DV_ = 32, R_ = 64;
constexpr float SCALE_ = 0.17677669529663687f;  // 1/sqrt(32)
constexpr float EPS_ = 1e-6f;

// ---------------------------------------------------------------------------
// K1: fused projection GEMM, 200 blocks (proven R4-R10).
__global__ __launch_bounds__(256) void projekev_kernel(
        const float* __restrict__ q, const float* __restrict__ Wq,
        const float* __restrict__ Wk, const float* __restrict__ Wv,
        const float* __restrict__ relE, const float* __restrict__ Wr,
        const float* __restrict__ Wvv, float* __restrict__ Xq,
        float* __restrict__ Xk, float* __restrict__ Xv,
        float* __restrict__ Ek, float* __restrict__ Ev) {
    int blk = blockIdx.x;
    int t = threadIdx.x;
    __shared__ __align__(16) float ash[32 * 65];
    __shared__ __align__(16) float bsh[32 * 64];
    const float *src, *W;
    int rowbase, cbase, ct;
    float* dstE = nullptr;
    if (blk < 192) {
        ct = blk >> 4;
        int rt = blk & 15;
        src = q; rowbase = rt * 64;
        if (ct < 4)      { W = Wq; cbase = ct * 64; }
        else if (ct < 8) { W = Wk; cbase = (ct - 4) * 64; }
        else             { W = Wv; cbase = (ct - 8) * 64; }
    } else {
        int e = blk - 192;           // 0..7
        src = relE; rowbase = 0; ct = -1;
        W = (e < 4) ? Wr : Wvv;
        dstE = (e < 4) ? Ek : Ev;
        cbase = (e & 3) * 64;
    }
    int ti = t >> 4, tj = t & 15;
    float acc[4][4] = {{0.f}};
    for (int kc = 0; kc < 8; ++kc) {
        __syncthreads();
#pragma unroll
        for (int kk = 0; kk < 2; ++kk) {
            int m = t + kk * 256;
            int i = m >> 3, kq = m & 7;
            float4 v = *(const float4*)(src + (size_t)(rowbase + i) * 256 + kc * 32 + kq * 4);
            ash[(kq * 4 + 0) * 65 + i] = v.x;
            ash[(kq * 4 + 1) * 65 + i] = v.y;
            ash[(kq * 4 + 2) * 65 + i] = v.z;
            ash[(kq * 4 + 3) * 65 + i] = v.w;
        }
#pragma unroll
        for (int kk = 0; kk < 2; ++kk) {
            int m = t + kk * 256;
            int k = m >> 4, j4 = m & 15;
            float4 v = *(const float4*)(W + (size_t)(kc * 32 + k) * 256 + cbase + j4 * 4);
            *(float4*)(bsh + k * 64 + j4 * 4) = v;
        }
        __syncthreads();
#pragma unroll 8
        for (int k = 0; k < 32; ++k) {
            float4 av = *(const float4*)(ash + k * 65 + ti * 4);
            float4 bv = *(const float4*)(bsh + k * 64 + tj * 4);
            acc[0][0] += av.x * bv.x; acc[0][1] += av.x * bv.y;
            acc[0][2] += av.x * bv.z; acc[0][3] += av.x * bv.w;
            acc[1][0] += av.y * bv.x; acc[1][1] += av.y * bv.y;
            acc[1][2] += av.y * bv.z; acc[1][3] += av.y * bv.w;
            acc[2][0] += av.z * bv.x; acc[2][1] += av.z * bv.y;
            acc[2][2] += av.z * bv.z; acc[2][3] += av.z * bv.w;
            acc[3][0] += av.w * bv.x; acc[3][1] += av.w * bv.y;
            acc[3][2] += av.w * bv.z; acc[3][3] += av.w * bv.w;
        }
    }
    if (dstE) {
#pragma unroll
        for (int a = 0; a < 4; ++a) {
            int row = ti * 4 + a;
            *(float4*)(dstE + (size_t)row * 256 + cbase + tj * 4) =
                make_float4(acc[a][0], acc[a][1], acc[a][2], acc[a][3]);
        }
    } else {
        float* dst = (ct < 4) ? Xq : (ct < 8) ? Xk : Xv;
        int gcol = (ct & 3) * 64 + tj * 4;
        int h = gcol >> 5, dk = gcol & 31;
#pragma unroll
        for (int a = 0; a < 4; ++a) {
            int row = rowbase + ti * 4 + a;
            int bb = row >> 8, n = row & 255;
            *(float4*)(dst + ((size_t)(bb * 8 + h) * 256 + n) * 32 + dk) =
                make_float4(acc[a][0], acc[a][1], acc[a][2], acc[a][3]);
        }
    }
}

// ---------------------------------------------------------------------------
// K2: balanced grid = 640: 512 qk tiles + 128 T tiles (proven R10).
__global__ __launch_bounds__(256) void qkT_kernel(
        const float* __restrict__ Xq, const float* __restrict__ Xk,
        const float* __restrict__ Ek, float* __restrict__ qk,
        float* __restrict__ T) {
    int x = blockIdx.x;
    int t = threadIdx.x;
    __shared__ __align__(16) float xqsh[32 * 64];
    __shared__ __align__(16) float bsh2[32 * 64];
    bool isT = (x >= 512);
    int jt, it, bh;
    if (!isT) { jt = x & 3; it = (x >> 2) & 3; bh = x >> 4; }
    else      { int e = x - 512; jt = 0; it = e & 3; bh = e >> 2; }
    int b = bh >> 3, h = bh & 7;
#pragma unroll
    for (int k = 0; k < 2; ++k) {
        int m = t + k * 256;
        int i = m >> 3, dq4 = m & 7;
        float4 v = *(const float4*)(Xq + ((size_t)(bh * 256 + it * 64 + i)) * 32 + dq4 * 4);
        xqsh[(dq4 * 4 + 0) * 64 + i] = v.x;
        xqsh[(dq4 * 4 + 1) * 64 + i] = v.y;
        xqsh[(dq4 * 4 + 2) * 64 + i] = v.z;
        xqsh[(dq4 * 4 + 3) * 64 + i] = v.w;
    }
    if (!isT) {
#pragma unroll
        for (int k = 0; k < 2; ++k) {
            int m = t + k * 256;
            int i = m >> 3, dq4 = m & 7;
            float4 u = *(const float4*)(Xk + ((size_t)(bh * 256 + jt * 64 + i)) * 32 + dq4 * 4);
            bsh2[(dq4 * 4 + 0) * 64 + i] = u.x;
            bsh2[(dq4 * 4 + 1) * 64 + i] = u.y;
            bsh2[(dq4 * 4 + 2) * 64 + i] = u.z;
            bsh2[(dq4 * 4 + 3) * 64 + i] = u.w;
        }
    } else {
        int r = t >> 2, dq = t & 3;
#pragma unroll
        for (int kk = 0; kk < 2; ++kk) {
            int dq4 = dq + kk * 4;  // 0..7
            float4 v = *(const float4*)(Ek + r * 256 + h * 32 + dq4 * 4);
            bsh2[(dq4 * 4 + 0) * 64 + r] = v.x;
            bsh2[(dq4 * 4 + 1) * 64 + r] = v.y;
            bsh2[(dq4 * 4 + 2) * 64 + r] = v.z;
            bsh2[(dq4 * 4 + 3) * 64 + r] = v.w;
        }
    }
    __syncthreads();
    int ti = t >> 4, tj = t & 15;
    float acc[4][4] = {{0.f}};
#pragma unroll 8
    for (int dk = 0; dk < 32; ++dk) {
        float4 av = *(const float4*)(xqsh + dk * 64 + ti * 4);
        float4 bv = *(const float4*)(bsh2 + dk * 64 + tj * 4);
        acc[0][0] += av.x * bv.x; acc[0][1] += av.x * bv.y;
        acc[0][2] += av.x * bv.z; acc[0][3] += av.x * bv.w;
        acc[1][0] += av.y * bv.x; acc[1][1] += av.y * bv.y;
        acc[1][2] += av.y * bv.z; acc[1][3] += av.y * bv.w;
        acc[2][0] += av.z * bv.x; acc[2][1] += av.z * bv.y;
        acc[2][2] += av.z * bv.z; acc[2][3] += av.z * bv.w;
        acc[3][0] += av.w * bv.x; acc[3][1] += av.w * bv.y;
        acc[3][2] += av.w * bv.z; acc[3][3] += av.w * bv.w;
    }
    if (!isT) {
#pragma unroll
        for (int a = 0; a < 4; ++a) {
            int i = it * 64 + ti * 4 + a;
            *(float4*)(qk + ((size_t)(bh * 256 + i)) * 256 + jt * 64 + tj * 4) =
                make_float4(acc[a][0], acc[a][1], acc[a][2], acc[a][3]);
        }
    } else {
#pragma unroll
        for (int a = 0; a < 4; ++a) {
            int i = it * 64 + ti * 4 + a;
            *(float4*)(T + ((size_t)(b * 256 + i)) * 512 + h * 64 + tj * 4) =
                make_float4(acc[a][0], acc[a][1], acc[a][2], acc[a][3]);
        }
    }
}

// ---------------------------------------------------------------------------
// K3: single-pass link kernel + last-block finalize. Block = (bi, jc).
// Per chunk: bias+exp (no-max, exact here), alphaU, esum, S in LDS (overwrites
// dead T rows, wave-local), S_jc.Ev folded into the Z partial (S is linear in
// chunks -> Spart buffer eliminated), Z-alpha partials -> Zpart.
// Then atomicAdd(cnt[bi]); the 4th arrival finalizes the row in-kernel:
// esum -> inv, Zq reduce (L2, same XCD via swizzle), alpha normalize,
// Wo GEMM + residual + LN -> out. No spin: losers exit. 4 KB cnt memset
// per launch (hipMemsetAsync, graph-capturable).
__global__ __launch_bounds__(256) void expszfin_kernel(
        const float* __restrict__ link, const float* __restrict__ Tg,
        const float* __restrict__ qk, const int* __restrict__ mask,
        const float* __restrict__ Xv, const float* __restrict__ Ev,
        const float* __restrict__ Wo, const float* __restrict__ q,
        const float* __restrict__ gamma, const float* __restrict__ beta,
        float* __restrict__ alpha, float* __restrict__ Zpart,
        float* __restrict__ esumP, int* __restrict__ cnt,
        float* __restrict__ out) {
    // bijective XCD swizzle: 4096 = 8*512; the 4 jc blocks of a row adjacent.
    int v = ((blockIdx.x & 7) << 9) | (blockIdx.x >> 3);
    int bi = v >> 2, jc = v & 3;
    int b = bi >> 8, i = bi & 255;
    int t = threadIdx.x;
    int g = t >> 6, jl = t & 63;         // wave, lane (= local j / r)
    int j0 = jc * 64;
    int h0 = g * 2, h1 = g * 2 + 1;      // wave g owns heads 2g, 2g+1

    __shared__ __align__(16) float linksh[64 * 68];  // [j][r], pad 68
    __shared__ __align__(16) float Tsh[8 * 68];      // T; S overwrites (wave-local)
    __shared__ __align__(16) float expsh[8 * 66];
    __shared__ __align__(16) float zshf[4 * 264];    // Z-alpha partials (scalar)
    __shared__ int finflag;

    {
        const float4* lp4 = (const float4*)(link + ((size_t)bi * 256 + j0) * 64);
#pragma unroll
        for (int k = 0; k < 4; ++k) {
            int m = t + k * 256;
            int j = m >> 4, rq = m & 15;
            *(float4*)(linksh + j * 68 + rq * 4) = lp4[m];
        }
    }
    for (int m = t; m < 512; m += 256)
        Tsh[(m >> 6) * 68 + (m & 63)] = Tg[(size_t)bi * 512 + m];
    float qv0 = qk[((size_t)(b * 8 + h0) * 256 + i) * 256 + j0 + jl];
    float qv1 = qk[((size_t)(b * 8 + h1) * 256 + i) * 256 + j0 + jl];
    int mv = mask[((size_t)(b * 256 + i)) * 256 + j0 + jl];
    __syncthreads();                                             // B1

    // ---- bias + exp (thread: j = j0+jl, heads h0,h1) ----
    float s0 = 0.f, s1 = 0.f;
    {
        const float4* lr = (const float4*)(linksh + jl * 68);
        const float4* t0 = (const float4*)(Tsh + h0 * 68);
        const float4* t1 = (const float4*)(Tsh + h1 * 68);
#pragma unroll
        for (int rq = 0; rq < 16; ++rq) {
            float4 lv = lr[rq];
            float4 a0 = t0[rq], a1 = t1[rq];
            s0 += lv.x * a0.x + lv.y * a0.y + lv.z * a0.z + lv.w * a0.w;
            s1 += lv.x * a1.x + lv.y * a1.y + lv.z * a1.z + lv.w * a1.w;
        }
    }
    s0 = (qv0 + s0) * SCALE_;
    s1 = (qv1 + s1) * SCALE_;
    if (mv == 0) { s0 = -1e9f; s1 = -1e9f; }
    float e0 = __expf(s0), e1 = __expf(s1);
    expsh[h0 * 66 + jl] = e0;
    expsh[h1 * 66 + jl] = e1;
    alpha[((size_t)(b * 8 + h0) * 256 + i) * 256 + j0 + jl] = e0;
    alpha[((size_t)(b * 8 + h1) * 256 + i) * 256 + j0 + jl] = e1;
    {   // per-chunk esums
        float v0 = e0, v1 = e1;
        for (int off = 32; off > 0; off >>= 1) {
            v0 += __shfl_xor(v0, off);
            v1 += __shfl_xor(v1, off);
        }
        if (jl == 0) {
            esumP[((size_t)bi * 4 + jc) * 8 + h0] = v0;
            esumP[((size_t)bi * 4 + jc) * 8 + h1] = v1;
        }
    }
    __syncthreads();                                             // B2 (expsh)

    // ---- S chunk into Tsh rows h0,h1 (wave-local: wave g owns those rows) --
    {
        float acc0 = 0.f, acc1 = 0.f;
        const float* ls = linksh + jl;           // lane = r
        const float* e0p = expsh + h0 * 66;
        const float* e1p = expsh + h1 * 66;
#pragma unroll 8
        for (int j = 0; j < 64; ++j) {
            float lv = ls[j * 68];
            acc0 += e0p[j] * lv;
            acc1 += e1p[j] * lv;
        }
        Tsh[h0 * 68 + jl] = acc0;                // T dead for this wave
        Tsh[h1 * 68 + jl] = acc1;
    }

    // ---- S_jc . Ev folded into Z (thread t -> col t = h*32+dv) ----
    float zsev = 0.f;
    {
        const float* sp = Tsh + (t >> 5) * 68;   // own-wave rows (wave-sync ok)
        const float* evp = Ev + t;               // coalesced, L2-hot
#pragma unroll 4
        for (int r = 0; r < 64; ++r) zsev += sp[r] * evp[(size_t)r * 256];
    }

    // ---- Z-alpha partials: wave g owns j-quarter [16g,16g+16) ----
    {
        int o = jl;
        int h = o >> 3, dv4 = o & 7;
        const float4* xv4 = (const float4*)Xv +
            (((size_t)(b * 8 + h)) * 256 + j0 + g * 16) * 8 + dv4;
        const float* ep = expsh + h * 66 + g * 16;
        float4 z = make_float4(0.f, 0.f, 0.f, 0.f);
#pragma unroll
        for (int j = 0; j < 16; ++j) {
            float a = ep[j];
            float4 x = xv4[j * 8];
            z.x += a * x.x; z.y += a * x.y; z.z += a * x.z; z.w += a * x.w;
        }
        *(float4*)(zshf + g * 264 + o * 4) = z;  // element index o*4+c == t
    }
    __syncthreads();                                             // B3
    {
        float zq = zsev + zshf[t] + zshf[264 + t] + zshf[528 + t] + zshf[792 + t];
        Zpart[((size_t)bi * 4 + jc) * 256 + t] = zq;
    }

    // ---- last-block-arrives finalize ----
    __threadfence();                 // release: all our global writes visible
    __syncthreads();                 // all threads' stores+fences done
    if (t == 0) {
        int old = atomicAdd(cnt + bi, 1);
        finflag = (old == 3) ? 1 : 0;
    }
    __syncthreads();                                             // B4
    if (!finflag) return;
    __threadfence();                 // acquire: siblings' writes visible

    // LDS reuse (linksh dead): zrow[256] | invl[8] | redl[16]
    float* zrow = linksh;
    float* invl = linksh + 256;
    float* redl = linksh + 272;
    if (t < 8) {
        float es = esumP[((size_t)bi * 4 + 0) * 8 + t] +
                   esumP[((size_t)bi * 4 + 1) * 8 + t] +
                   esumP[((size_t)bi * 4 + 2) * 8 + t] +
                   esumP[((size_t)bi * 4 + 3) * 8 + t];
        invl[t] = 1.f / es;
    }
    __syncthreads();                                             // B5
    {
        float zq = Zpart[((size_t)bi * 4 + 0) * 256 + t] +
                   Zpart[((size_t)bi * 4 + 1) * 256 + t] +
                   Zpart[((size_t)bi * 4 + 2) * 256 + t] +
                   Zpart[((size_t)bi * 4 + 3) * 256 + t];
        zrow[t] = zq * invl[t >> 5];
    }
#pragma unroll
    for (int k = 0; k < 8; ++k) {    // normalize alpha row (L2-hot)
        size_t off = ((size_t)(b * 8 + k) * 256 + i) * 256 + t;
        alpha[off] *= invl[k];
    }
    __syncthreads();                                             // B6
    // ---- out = LN(zrow @ Wo + q) ----
    float a = q[(size_t)bi * 256 + t];
    {
        const float4* z4 = (const float4*)zrow;
        const float* wp = Wo + t;
#pragma unroll 4
        for (int d4 = 0; d4 < 64; ++d4) {
            float4 zz = z4[d4];
            a += zz.x * wp[(d4 * 4 + 0) * 256] + zz.y * wp[(d4 * 4 + 1) * 256] +
                 zz.z * wp[(d4 * 4 + 2) * 256] + zz.w * wp[(d4 * 4 + 3) * 256];
        }
    }
    {
        float v2 = a, vq = a * a;
        for (int off = 32; off > 0; off >>= 1) {
            v2 += __shfl_xor(v2, off);
            vq += __shfl_xor(vq, off);
        }
        if (jl == 0) { redl[g] = v2; redl[8 + g] = vq; }
    }
    __syncthreads();                                             // B7
    {
        float sum = redl[0] + redl[1] + redl[2] + redl[3];
        float sum2 = redl[8] + redl[9] + redl[10] + redl[11];
        float mu = sum * (1.f / 256.f);
        float var = sum2 * (1.f / 256.f) - mu * mu;
        out[(size_t)bi * 256 + t] = (a - mu) * rsqrtf(var + EPS_) * gamma[t] + beta[t];
    }
}

// ---------------------------------------------------------------------------
extern "C" void kernel_launch(void* const* d_in, const int* in_sizes, int n_in,
                              void* d_out, int out_size, void* d_ws, size_t ws_size,
                              hipStream_t stream) {
    const float* q     = (const float*)d_in[0];
    const int*   mask  = (const int*)d_in[3];
    const float* link  = (const float*)d_in[4];
    const float* Wq    = (const float*)d_in[5];
    const float* Wk    = (const float*)d_in[6];
    const float* Wr    = (const float*)d_in[7];
    const float* Wv    = (const float*)d_in[8];
    const float* Wvv   = (const float*)d_in[9];
    const float* relE  = (const float*)d_in[10];
    const float* Wo    = (const float*)d_in[11];
    const float* gamma = (const float*)d_in[12];
    const float* beta  = (const float*)d_in[13];

    float* out   = (float*)d_out;
    float* alpha = out + B_ * N_ * D_;      // second output [B,H,N,N]

    float* ws = (float*)d_ws;
    float* Ek    = ws;                  // 16384
    float* Ev    = Ek + 16384;          // 16384
    float* Xq    = Ev + 16384;          // 262144
    float* Xk    = Xq + 262144;         // 262144
    float* Xv    = Xk + 262144;         // 262144
    float* T     = Xv + 262144;         // 524288
    float* qkbuf = T + 524288;          // 2097152
    float* Zpart = qkbuf + 2097152;     // 1048576
    float* esumP = Zpart + 1048576;     // 32768
    int*   cnt   = (int*)(esumP + 32768); // 1024 ints (total ~18 MB)

    hipMemsetAsync(cnt, 0, 1024 * sizeof(int), stream);
    projekev_kernel<<<200, 256, 0, stream>>>(q, Wq, Wk, Wv, relE, Wr, Wvv,
                                             Xq, Xk, Xv, Ek, Ev);
    qkT_kernel<<<640, 256, 0, stream>>>(Xq, Xk, Ek, qkbuf, T);
    expszfin_kernel<<<4096, 256, 0, stream>>>(link, T, qkbuf, mask, Xv, Ev,
                                              Wo, q, gamma, beta, alpha,
                                              Zpart, esumP, cnt, out);
}

// Round 12
// 188.603 us; speedup vs baseline: 3.7667x; 3.7667x over previous
//
#include <hip/hip_runtime.h>
#include <math.h>

// B=4, N=256, D=256, H=8, DK=32, DV=32, R=64
constexpr int B_ = 4, N_ = 256, D_ = 256, H_ = 8, DK_ = 32, DV_ = 32, R_ = 64;
constexpr float SCALE_ = 0.17677669529663687f;  // 1/sqrt(32)
constexpr float EPS_ = 1e-6f;

// ---------------------------------------------------------------------------
// K1: fused projection GEMM, 200 blocks (proven R4-R10).
__global__ __launch_bounds__(256) void projekev_kernel(
        const float* __restrict__ q, const float* __restrict__ Wq,
        const float* __restrict__ Wk, const float* __restrict__ Wv,
        const float* __restrict__ relE, const float* __restrict__ Wr,
        const float* __restrict__ Wvv, float* __restrict__ Xq,
        float* __restrict__ Xk, float* __restrict__ Xv,
        float* __restrict__ Ek, float* __restrict__ Ev) {
    int blk = blockIdx.x;
    int t = threadIdx.x;
    __shared__ __align__(16) float ash[32 * 65];
    __shared__ __align__(16) float bsh[32 * 64];
    const float *src, *W;
    int rowbase, cbase, ct;
    float* dstE = nullptr;
    if (blk < 192) {
        ct = blk >> 4;
        int rt = blk & 15;
        src = q; rowbase = rt * 64;
        if (ct < 4)      { W = Wq; cbase = ct * 64; }
        else if (ct < 8) { W = Wk; cbase = (ct - 4) * 64; }
        else             { W = Wv; cbase = (ct - 8) * 64; }
    } else {
        int e = blk - 192;           // 0..7
        src = relE; rowbase = 0; ct = -1;
        W = (e < 4) ? Wr : Wvv;
        dstE = (e < 4) ? Ek : Ev;
        cbase = (e & 3) * 64;
    }
    int ti = t >> 4, tj = t & 15;
    float acc[4][4] = {{0.f}};
    for (int kc = 0; kc < 8; ++kc) {
        __syncthreads();
#pragma unroll
        for (int kk = 0; kk < 2; ++kk) {
            int m = t + kk * 256;
            int i = m >> 3, kq = m & 7;
            float4 v = *(const float4*)(src + (size_t)(rowbase + i) * 256 + kc * 32 + kq * 4);
            ash[(kq * 4 + 0) * 65 + i] = v.x;
            ash[(kq * 4 + 1) * 65 + i] = v.y;
            ash[(kq * 4 + 2) * 65 + i] = v.z;
            ash[(kq * 4 + 3) * 65 + i] = v.w;
        }
#pragma unroll
        for (int kk = 0; kk < 2; ++kk) {
            int m = t + kk * 256;
            int k = m >> 4, j4 = m & 15;
            float4 v = *(const float4*)(W + (size_t)(kc * 32 + k) * 256 + cbase + j4 * 4);
            *(float4*)(bsh + k * 64 + j4 * 4) = v;
        }
        __syncthreads();
#pragma unroll 8
        for (int k = 0; k < 32; ++k) {
            float4 av = *(const float4*)(ash + k * 65 + ti * 4);
            float4 bv = *(const float4*)(bsh + k * 64 + tj * 4);
            acc[0][0] += av.x * bv.x; acc[0][1] += av.x * bv.y;
            acc[0][2] += av.x * bv.z; acc[0][3] += av.x * bv.w;
            acc[1][0] += av.y * bv.x; acc[1][1] += av.y * bv.y;
            acc[1][2] += av.y * bv.z; acc[1][3] += av.y * bv.w;
            acc[2][0] += av.z * bv.x; acc[2][1] += av.z * bv.y;
            acc[2][2] += av.z * bv.z; acc[2][3] += av.z * bv.w;
            acc[3][0] += av.w * bv.x; acc[3][1] += av.w * bv.y;
            acc[3][2] += av.w * bv.z; acc[3][3] += av.w * bv.w;
        }
    }
    if (dstE) {
#pragma unroll
        for (int a = 0; a < 4; ++a) {
            int row = ti * 4 + a;
            *(float4*)(dstE + (size_t)row * 256 + cbase + tj * 4) =
                make_float4(acc[a][0], acc[a][1], acc[a][2], acc[a][3]);
        }
    } else {
        float* dst = (ct < 4) ? Xq : (ct < 8) ? Xk : Xv;
        int gcol = (ct & 3) * 64 + tj * 4;
        int h = gcol >> 5, dk = gcol & 31;
#pragma unroll
        for (int a = 0; a < 4; ++a) {
            int row = rowbase + ti * 4 + a;
            int bb = row >> 8, n = row & 255;
            *(float4*)(dst + ((size_t)(bb * 8 + h) * 256 + n) * 32 + dk) =
                make_float4(acc[a][0], acc[a][1], acc[a][2], acc[a][3]);
        }
    }
}

// ---------------------------------------------------------------------------
// K2: balanced grid = 640: 512 qk tiles + 128 T tiles (proven R10).
__global__ __launch_bounds__(256) void qkT_kernel(
        const float* __restrict__ Xq, const float* __restrict__ Xk,
        const float* __restrict__ Ek, float* __restrict__ qk,
        float* __restrict__ T) {
    int x = blockIdx.x;
    int t = threadIdx.x;
    __shared__ __align__(16) float xqsh[32 * 64];
    __shared__ __align__(16) float bsh2[32 * 64];
    bool isT = (x >= 512);
    int jt, it, bh;
    if (!isT) { jt = x & 3; it = (x >> 2) & 3; bh = x >> 4; }
    else      { int e = x - 512; jt = 0; it = e & 3; bh = e >> 2; }
    int b = bh >> 3, h = bh & 7;
#pragma unroll
    for (int k = 0; k < 2; ++k) {
        int m = t + k * 256;
        int i = m >> 3, dq4 = m & 7;
        float4 v = *(const float4*)(Xq + ((size_t)(bh * 256 + it * 64 + i)) * 32 + dq4 * 4);
        xqsh[(dq4 * 4 + 0) * 64 + i] = v.x;
        xqsh[(dq4 * 4 + 1) * 64 + i] = v.y;
        xqsh[(dq4 * 4 + 2) * 64 + i] = v.z;
        xqsh[(dq4 * 4 + 3) * 64 + i] = v.w;
    }
    if (!isT) {
#pragma unroll
        for (int k = 0; k < 2; ++k) {
            int m = t + k * 256;
            int i = m >> 3, dq4 = m & 7;
            float4 u = *(const float4*)(Xk + ((size_t)(bh * 256 + jt * 64 + i)) * 32 + dq4 * 4);
            bsh2[(dq4 * 4 + 0) * 64 + i] = u.x;
            bsh2[(dq4 * 4 + 1) * 64 + i] = u.y;
            bsh2[(dq4 * 4 + 2) * 64 + i] = u.z;
            bsh2[(dq4 * 4 + 3) * 64 + i] = u.w;
        }
    } else {
        int r = t >> 2, dq = t & 3;
#pragma unroll
        for (int kk = 0; kk < 2; ++kk) {
            int dq4 = dq + kk * 4;  // 0..7
            float4 v = *(const float4*)(Ek + r * 256 + h * 32 + dq4 * 4);
            bsh2[(dq4 * 4 + 0) * 64 + r] = v.x;
            bsh2[(dq4 * 4 + 1) * 64 + r] = v.y;
            bsh2[(dq4 * 4 + 2) * 64 + r] = v.z;
            bsh2[(dq4 * 4 + 3) * 64 + r] = v.w;
        }
    }
    __syncthreads();
    int ti = t >> 4, tj = t & 15;
    float acc[4][4] = {{0.f}};
#pragma unroll 8
    for (int dk = 0; dk < 32; ++dk) {
        float4 av = *(const float4*)(xqsh + dk * 64 + ti * 4);
        float4 bv = *(const float4*)(bsh2 + dk * 64 + tj * 4);
        acc[0][0] += av.x * bv.x; acc[0][1] += av.x * bv.y;
        acc[0][2] += av.x * bv.z; acc[0][3] += av.x * bv.w;
        acc[1][0] += av.y * bv.x; acc[1][1] += av.y * bv.y;
        acc[1][2] += av.y * bv.z; acc[1][3] += av.y * bv.w;
        acc[2][0] += av.z * bv.x; acc[2][1] += av.z * bv.y;
        acc[2][2] += av.z * bv.z; acc[2][3] += av.z * bv.w;
        acc[3][0] += av.w * bv.x; acc[3][1] += av.w * bv.y;
        acc[3][2] += av.w * bv.z; acc[3][3] += av.w * bv.w;
    }
    if (!isT) {
#pragma unroll
        for (int a = 0; a < 4; ++a) {
            int i = it * 64 + ti * 4 + a;
            *(float4*)(qk + ((size_t)(bh * 256 + i)) * 256 + jt * 64 + tj * 4) =
                make_float4(acc[a][0], acc[a][1], acc[a][2], acc[a][3]);
        }
    } else {
#pragma unroll
        for (int a = 0; a < 4; ++a) {
            int i = it * 64 + ti * 4 + a;
            *(float4*)(T + ((size_t)(b * 256 + i)) * 512 + h * 64 + tj * 4) =
                make_float4(acc[a][0], acc[a][1], acc[a][2], acc[a][3]);
        }
    }
}

// ---------------------------------------------------------------------------
// K3: single-pass link kernel, ONE barrier. Block = (bi, jc): 64 j's, 8 h.
// After B1 every phase is wave-local: wave g owns heads {2g, 2g+1} for exp
// rows, S rows, AND the Z columns t = 64g..64g+63 map to h = t>>5 in {2g,2g+1}.
// S_jc.Ev is folded into the Z partial (S linear in chunks -> no Spart buffer;
// numerically verified in R11). No cross-block sync (R11's threadfence
// finalize cost 600 us in L2 writebacks — finalize stays a separate launch).
__global__ __launch_bounds__(256) void expsz_kernel(
        const float* __restrict__ link, const float* __restrict__ Tg,
        const float* __restrict__ qk, const int* __restrict__ mask,
        const float* __restrict__ Xv, const float* __restrict__ Ev,
        float* __restrict__ alphaU, float* __restrict__ Zpart,
        float* __restrict__ esumP) {
    // bijective XCD swizzle: 4096 = 8*512; the 4 jc blocks of a row adjacent.
    int v = ((blockIdx.x & 7) << 9) | (blockIdx.x >> 3);
    int bi = v >> 2, jc = v & 3;
    int b = bi >> 8, i = bi & 255;
    int t = threadIdx.x;
    int g = t >> 6, jl = t & 63;         // wave, lane (= local j / r)
    int j0 = jc * 64;
    int h0 = g * 2, h1 = g * 2 + 1;      // wave g owns heads 2g, 2g+1

    __shared__ __align__(16) float linksh[64 * 68];  // [j][r], pad 68
    __shared__ __align__(16) float Tsh[8 * 68];      // T; S overwrites (wave-local)
    __shared__ __align__(16) float expsh[8 * 66];    // exp rows (wave-local)

    {
        const float4* lp4 = (const float4*)(link + ((size_t)bi * 256 + j0) * 64);
#pragma unroll
        for (int k = 0; k < 4; ++k) {
            int m = t + k * 256;
            int j = m >> 4, rq = m & 15;
            *(float4*)(linksh + j * 68 + rq * 4) = lp4[m];
        }
    }
    for (int m = t; m < 512; m += 256)
        Tsh[(m >> 6) * 68 + (m & 63)] = Tg[(size_t)bi * 512 + m];
    float qv0 = qk[((size_t)(b * 8 + h0) * 256 + i) * 256 + j0 + jl];
    float qv1 = qk[((size_t)(b * 8 + h1) * 256 + i) * 256 + j0 + jl];
    int mv = mask[((size_t)(b * 256 + i)) * 256 + j0 + jl];
    __syncthreads();                                             // B1 (only)

    // ---- bias + exp (thread: j = j0+jl, heads h0,h1) ----
    float s0 = 0.f, s1 = 0.f;
    {
        const float4* lr = (const float4*)(linksh + jl * 68);
        const float4* t0 = (const float4*)(Tsh + h0 * 68);
        const float4* t1 = (const float4*)(Tsh + h1 * 68);
#pragma unroll
        for (int rq = 0; rq < 16; ++rq) {
            float4 lv = lr[rq];
            float4 a0 = t0[rq], a1 = t1[rq];
            s0 += lv.x * a0.x + lv.y * a0.y + lv.z * a0.z + lv.w * a0.w;
            s1 += lv.x * a1.x + lv.y * a1.y + lv.z * a1.z + lv.w * a1.w;
        }
    }
    s0 = (qv0 + s0) * SCALE_;
    s1 = (qv1 + s1) * SCALE_;
    if (mv == 0) { s0 = -1e9f; s1 = -1e9f; }
    float e0 = __expf(s0), e1 = __expf(s1);
    expsh[h0 * 66 + jl] = e0;
    expsh[h1 * 66 + jl] = e1;
    alphaU[((size_t)(b * 8 + h0) * 256 + i) * 256 + j0 + jl] = e0;
    alphaU[((size_t)(b * 8 + h1) * 256 + i) * 256 + j0 + jl] = e1;
    {   // per-chunk esums (wave-local shfl)
        float v0 = e0, v1 = e1;
        for (int off = 32; off > 0; off >>= 1) {
            v0 += __shfl_xor(v0, off);
            v1 += __shfl_xor(v1, off);
        }
        if (jl == 0) {
            esumP[((size_t)bi * 4 + jc) * 8 + h0] = v0;
            esumP[((size_t)bi * 4 + jc) * 8 + h1] = v1;
        }
    }

    // ---- S chunk into Tsh rows h0,h1 (wave-local; lane = r) ----
    {
        float acc0 = 0.f, acc1 = 0.f;
        const float* ls = linksh + jl;
        const float* e0p = expsh + h0 * 66;    // own-wave rows
        const float* e1p = expsh + h1 * 66;
#pragma unroll 8
        for (int j = 0; j < 64; ++j) {
            float lv = ls[j * 68];
            acc0 += e0p[j] * lv;
            acc1 += e1p[j] * lv;
        }
        Tsh[h0 * 68 + jl] = acc0;              // T rows dead for this wave
        Tsh[h1 * 68 + jl] = acc1;
    }

    // ---- Z column t: h = t>>5 in {h0,h1} (own wave), dv = t&31 ----
    {
        int h = t >> 5, dv = t & 31;
        // S_jc . Ev (S rows just written by this wave)
        float z = 0.f;
        const float* sp = Tsh + h * 68;
        const float* evp = Ev + t;             // coalesced, L2-hot
#pragma unroll 4
        for (int r = 0; r < 64; ++r) z += sp[r] * evp[(size_t)r * 256];
        // alpha-part: sum_j exp[h][j] * Xv[b,h,j0+j,dv]
        const float* ep = expsh + h * 66;      // broadcast within lane-group
        const float* xvp = Xv + (((size_t)(b * 8 + h)) * 256 + j0) * 32 + dv;
#pragma unroll 8
        for (int j = 0; j < 64; ++j) z += ep[j] * xvp[j * 32];
        Zpart[((size_t)bi * 4 + jc) * 256 + t] = z;
    }
}

// ---------------------------------------------------------------------------
// K4: finalize + output. grid = 512 (2 rows each), block = 256.
// Per row: inv from esumP, Z = sum(Zpart)*inv -> LDS, alpha normalize (L2-hot);
// then Z @ Wo + residual + LN for both rows.
__global__ __launch_bounds__(256) void finout_kernel(
        const float* __restrict__ Zpart, const float* __restrict__ esumP,
        const float* __restrict__ Wo, const float* __restrict__ q,
        const float* __restrict__ gamma, const float* __restrict__ beta,
        float* __restrict__ alpha, float* __restrict__ out) {
    int row0 = blockIdx.x * 2;
    int b = row0 >> 8;
    int t = threadIdx.x;
    int lane = t & 63, wv = t >> 6;
    __shared__ __align__(16) float zsh[512];
    __shared__ float invsh[16];
    __shared__ float redsh[16];

#pragma unroll
    for (int rr = 0; rr < 2; ++rr) {
        int row = row0 + rr;
        int i = row & 255;
        if (t < 8) {
            float es = esumP[((size_t)row * 4 + 0) * 8 + t] +
                       esumP[((size_t)row * 4 + 1) * 8 + t] +
                       esumP[((size_t)row * 4 + 2) * 8 + t] +
                       esumP[((size_t)row * 4 + 3) * 8 + t];
            invsh[rr * 8 + t] = 1.f / es;
        }
        __syncthreads();
        {
            float zq = Zpart[((size_t)row * 4 + 0) * 256 + t] +
                       Zpart[((size_t)row * 4 + 1) * 256 + t] +
                       Zpart[((size_t)row * 4 + 2) * 256 + t] +
                       Zpart[((size_t)row * 4 + 3) * 256 + t];
            zsh[rr * 256 + t] = zq * invsh[rr * 8 + (t >> 5)];
        }
#pragma unroll
        for (int k = 0; k < 8; ++k) {
            size_t off = ((size_t)(b * 8 + k) * 256 + i) * 256 + t;
            alpha[off] *= invsh[rr * 8 + k];
        }
    }
    __syncthreads();

    // ---- out = LN(Z @ Wo + q) for both rows ----
    float a0 = q[(size_t)row0 * 256 + t];
    float a1 = q[(size_t)(row0 + 1) * 256 + t];
    for (int d4 = 0; d4 < 64; ++d4) {
        float w0 = Wo[(d4 * 4 + 0) * 256 + t];
        float w1 = Wo[(d4 * 4 + 1) * 256 + t];
        float w2 = Wo[(d4 * 4 + 2) * 256 + t];
        float w3 = Wo[(d4 * 4 + 3) * 256 + t];
        float4 z0v = *(const float4*)(zsh + d4 * 4);
        float4 z1v = *(const float4*)(zsh + 256 + d4 * 4);
        a0 += z0v.x * w0 + z0v.y * w1 + z0v.z * w2 + z0v.w * w3;
        a1 += z1v.x * w0 + z1v.y * w1 + z1v.z * w2 + z1v.w * w3;
    }
    float acc2[2] = {a0, a1};
#pragma unroll
    for (int rr = 0; rr < 2; ++rr) {
        float v = acc2[rr], v2 = acc2[rr] * acc2[rr];
        for (int off = 32; off > 0; off >>= 1) {
            v += __shfl_xor(v, off);
            v2 += __shfl_xor(v2, off);
        }
        if (lane == 0) {
            redsh[rr * 8 + wv] = v;
            redsh[rr * 8 + 4 + wv] = v2;
        }
    }
    __syncthreads();
#pragma unroll
    for (int rr = 0; rr < 2; ++rr) {
        float sum = redsh[rr * 8 + 0] + redsh[rr * 8 + 1] + redsh[rr * 8 + 2] + redsh[rr * 8 + 3];
        float sum2 = redsh[rr * 8 + 4] + redsh[rr * 8 + 5] + redsh[rr * 8 + 6] + redsh[rr * 8 + 7];
        float mu = sum * (1.f / 256.f);
        float var = sum2 * (1.f / 256.f) - mu * mu;
        float dev = acc2[rr] - mu;
        out[(size_t)(row0 + rr) * 256 + t] = dev * rsqrtf(var + EPS_) * gamma[t] + beta[t];
    }
}

// ---------------------------------------------------------------------------
extern "C" void kernel_launch(void* const* d_in, const int* in_sizes, int n_in,
                              void* d_out, int out_size, void* d_ws, size_t ws_size,
                              hipStream_t stream) {
    const float* q     = (const float*)d_in[0];
    const int*   mask  = (const int*)d_in[3];
    const float* link  = (const float*)d_in[4];
    const float* Wq    = (const float*)d_in[5];
    const float* Wk    = (const float*)d_in[6];
    const float* Wr    = (const float*)d_in[7];
    const float* Wv    = (const float*)d_in[8];
    const float* Wvv   = (const float*)d_in[9];
    const float* relE  = (const float*)d_in[10];
    const float* Wo    = (const float*)d_in[11];
    const float* gamma = (const float*)d_in[12];
    const float* beta  = (const float*)d_in[13];

    float* out   = (float*)d_out;
    float* alpha = out + B_ * N_ * D_;      // second output [B,H,N,N]

    float* ws = (float*)d_ws;
    float* Ek    = ws;                  // 16384
    float* Ev    = Ek + 16384;          // 16384
    float* Xq    = Ev + 16384;          // 262144
    float* Xk    = Xq + 262144;         // 262144
    float* Xv    = Xk + 262144;         // 262144
    float* T     = Xv + 262144;         // 524288
    float* qkbuf = T + 524288;          // 2097152
    float* Zpart = qkbuf + 2097152;     // 1048576
    float* esumP = Zpart + 1048576;     // 32768   (total ~18 MB)

    projekev_kernel<<<200, 256, 0, stream>>>(q, Wq, Wk, Wv, relE, Wr, Wvv,
                                             Xq, Xk, Xv, Ek, Ev);
    qkT_kernel<<<640, 256, 0, stream>>>(Xq, Xk, Ek, qkbuf, T);
    expsz_kernel<<<4096, 256, 0, stream>>>(link, T, qkbuf, mask, Xv, Ev,
                                           alpha, Zpart, esumP);
    finout_kernel<<<512, 256, 0, stream>>>(Zpart, esumP, Wo, q,
                                           gamma, beta, alpha, out);
}

// Round 13
// 184.092 us; speedup vs baseline: 3.8590x; 1.0245x over previous
//
#include <hip/hip_runtime.h>
#include <math.h>

// B=4, N=256, D=256, H=8, DK=32, DV=32, R=64
constexpr int B_ = 4, N_ = 256, D_ = 256, H_ = 8, DK_ = 32, DV_ = 32, R_ = 64;
constexpr float SCALE_ = 0.17677669529663687f;  // 1/sqrt(32)
constexpr float EPS_ = 1e-6f;

// ---------------------------------------------------------------------------
// K1: fused projection GEMM, 200 blocks (proven R4-R10).
__global__ __launch_bounds__(256) void projekev_kernel(
        const float* __restrict__ q, const float* __restrict__ Wq,
        const float* __restrict__ Wk, const float* __restrict__ Wv,
        const float* __restrict__ relE, const float* __restrict__ Wr,
        const float* __restrict__ Wvv, float* __restrict__ Xq,
        float* __restrict__ Xk, float* __restrict__ Xv,
        float* __restrict__ Ek, float* __restrict__ Ev) {
    int blk = blockIdx.x;
    int t = threadIdx.x;
    __shared__ __align__(16) float ash[32 * 65];
    __shared__ __align__(16) float bsh[32 * 64];
    const float *src, *W;
    int rowbase, cbase, ct;
    float* dstE = nullptr;
    if (blk < 192) {
        ct = blk >> 4;
        int rt = blk & 15;
        src = q; rowbase = rt * 64;
        if (ct < 4)      { W = Wq; cbase = ct * 64; }
        else if (ct < 8) { W = Wk; cbase = (ct - 4) * 64; }
        else             { W = Wv; cbase = (ct - 8) * 64; }
    } else {
        int e = blk - 192;           // 0..7
        src = relE; rowbase = 0; ct = -1;
        W = (e < 4) ? Wr : Wvv;
        dstE = (e < 4) ? Ek : Ev;
        cbase = (e & 3) * 64;
    }
    int ti = t >> 4, tj = t & 15;
    float acc[4][4] = {{0.f}};
    for (int kc = 0; kc < 8; ++kc) {
        __syncthreads();
#pragma unroll
        for (int kk = 0; kk < 2; ++kk) {
            int m = t + kk * 256;
            int i = m >> 3, kq = m & 7;
            float4 v = *(const float4*)(src + (size_t)(rowbase + i) * 256 + kc * 32 + kq * 4);
            ash[(kq * 4 + 0) * 65 + i] = v.x;
            ash[(kq * 4 + 1) * 65 + i] = v.y;
            ash[(kq * 4 + 2) * 65 + i] = v.z;
            ash[(kq * 4 + 3) * 65 + i] = v.w;
        }
#pragma unroll
        for (int kk = 0; kk < 2; ++kk) {
            int m = t + kk * 256;
            int k = m >> 4, j4 = m & 15;
            float4 v = *(const float4*)(W + (size_t)(kc * 32 + k) * 256 + cbase + j4 * 4);
            *(float4*)(bsh + k * 64 + j4 * 4) = v;
        }
        __syncthreads();
#pragma unroll 8
        for (int k = 0; k < 32; ++k) {
            float4 av = *(const float4*)(ash + k * 65 + ti * 4);
            float4 bv = *(const float4*)(bsh + k * 64 + tj * 4);
            acc[0][0] += av.x * bv.x; acc[0][1] += av.x * bv.y;
            acc[0][2] += av.x * bv.z; acc[0][3] += av.x * bv.w;
            acc[1][0] += av.y * bv.x; acc[1][1] += av.y * bv.y;
            acc[1][2] += av.y * bv.z; acc[1][3] += av.y * bv.w;
            acc[2][0] += av.z * bv.x; acc[2][1] += av.z * bv.y;
            acc[2][2] += av.z * bv.z; acc[2][3] += av.z * bv.w;
            acc[3][0] += av.w * bv.x; acc[3][1] += av.w * bv.y;
            acc[3][2] += av.w * bv.z; acc[3][3] += av.w * bv.w;
        }
    }
    if (dstE) {
#pragma unroll
        for (int a = 0; a < 4; ++a) {
            int row = ti * 4 + a;
            *(float4*)(dstE + (size_t)row * 256 + cbase + tj * 4) =
                make_float4(acc[a][0], acc[a][1], acc[a][2], acc[a][3]);
        }
    } else {
        float* dst = (ct < 4) ? Xq : (ct < 8) ? Xk : Xv;
        int gcol = (ct & 3) * 64 + tj * 4;
        int h = gcol >> 5, dk = gcol & 31;
#pragma unroll
        for (int a = 0; a < 4; ++a) {
            int row = rowbase + ti * 4 + a;
            int bb = row >> 8, n = row & 255;
            *(float4*)(dst + ((size_t)(bb * 8 + h) * 256 + n) * 32 + dk) =
                make_float4(acc[a][0], acc[a][1], acc[a][2], acc[a][3]);
        }
    }
}

// ---------------------------------------------------------------------------
// K2: balanced grid = 640: 512 qk tiles + 128 T tiles (proven R10).
__global__ __launch_bounds__(256) void qkT_kernel(
        const float* __restrict__ Xq, const float* __restrict__ Xk,
        const float* __restrict__ Ek, float* __restrict__ qk,
        float* __restrict__ T) {
    int x = blockIdx.x;
    int t = threadIdx.x;
    __shared__ __align__(16) float xqsh[32 * 64];
    __shared__ __align__(16) float bsh2[32 * 64];
    bool isT = (x >= 512);
    int jt, it, bh;
    if (!isT) { jt = x & 3; it = (x >> 2) & 3; bh = x >> 4; }
    else      { int e = x - 512; jt = 0; it = e & 3; bh = e >> 2; }
    int b = bh >> 3, h = bh & 7;
#pragma unroll
    for (int k = 0; k < 2; ++k) {
        int m = t + k * 256;
        int i = m >> 3, dq4 = m & 7;
        float4 v = *(const float4*)(Xq + ((size_t)(bh * 256 + it * 64 + i)) * 32 + dq4 * 4);
        xqsh[(dq4 * 4 + 0) * 64 + i] = v.x;
        xqsh[(dq4 * 4 + 1) * 64 + i] = v.y;
        xqsh[(dq4 * 4 + 2) * 64 + i] = v.z;
        xqsh[(dq4 * 4 + 3) * 64 + i] = v.w;
    }
    if (!isT) {
#pragma unroll
        for (int k = 0; k < 2; ++k) {
            int m = t + k * 256;
            int i = m >> 3, dq4 = m & 7;
            float4 u = *(const float4*)(Xk + ((size_t)(bh * 256 + jt * 64 + i)) * 32 + dq4 * 4);
            bsh2[(dq4 * 4 + 0) * 64 + i] = u.x;
            bsh2[(dq4 * 4 + 1) * 64 + i] = u.y;
            bsh2[(dq4 * 4 + 2) * 64 + i] = u.z;
            bsh2[(dq4 * 4 + 3) * 64 + i] = u.w;
        }
    } else {
        int r = t >> 2, dq = t & 3;
#pragma unroll
        for (int kk = 0; kk < 2; ++kk) {
            int dq4 = dq + kk * 4;  // 0..7
            float4 v = *(const float4*)(Ek + r * 256 + h * 32 + dq4 * 4);
            bsh2[(dq4 * 4 + 0) * 64 + r] = v.x;
            bsh2[(dq4 * 4 + 1) * 64 + r] = v.y;
            bsh2[(dq4 * 4 + 2) * 64 + r] = v.z;
            bsh2[(dq4 * 4 + 3) * 64 + r] = v.w;
        }
    }
    __syncthreads();
    int ti = t >> 4, tj = t & 15;
    float acc[4][4] = {{0.f}};
#pragma unroll 8
    for (int dk = 0; dk < 32; ++dk) {
        float4 av = *(const float4*)(xqsh + dk * 64 + ti * 4);
        float4 bv = *(const float4*)(bsh2 + dk * 64 + tj * 4);
        acc[0][0] += av.x * bv.x; acc[0][1] += av.x * bv.y;
        acc[0][2] += av.x * bv.z; acc[0][3] += av.x * bv.w;
        acc[1][0] += av.y * bv.x; acc[1][1] += av.y * bv.y;
        acc[1][2] += av.y * bv.z; acc[1][3] += av.y * bv.w;
        acc[2][0] += av.z * bv.x; acc[2][1] += av.z * bv.y;
        acc[2][2] += av.z * bv.z; acc[2][3] += av.z * bv.w;
        acc[3][0] += av.w * bv.x; acc[3][1] += av.w * bv.y;
        acc[3][2] += av.w * bv.z; acc[3][3] += av.w * bv.w;
    }
    if (!isT) {
#pragma unroll
        for (int a = 0; a < 4; ++a) {
            int i = it * 64 + ti * 4 + a;
            *(float4*)(qk + ((size_t)(bh * 256 + i)) * 256 + jt * 64 + tj * 4) =
                make_float4(acc[a][0], acc[a][1], acc[a][2], acc[a][3]);
        }
    } else {
#pragma unroll
        for (int a = 0; a < 4; ++a) {
            int i = it * 64 + ti * 4 + a;
            *(float4*)(T + ((size_t)(b * 256 + i)) * 512 + h * 64 + tj * 4) =
                make_float4(acc[a][0], acc[a][1], acc[a][2], acc[a][3]);
        }
    }
}

// ---------------------------------------------------------------------------
// K3: single-pass link chunk kernel (R10-proven: 40.7 us). Block = (bi, jc).
// Stages link[64j][64r] in LDS once; bias + exp (no max-subtraction — exact
// here, masked -> 0); unnormalized alpha; per-chunk esums; S partials from
// the SAME LDS tile -> Spart; Z-alpha partials (float4 Xv) -> Zpart.
__global__ __launch_bounds__(256) void expsz_kernel(
        const float* __restrict__ link, const float* __restrict__ Tg,
        const float* __restrict__ qk, const int* __restrict__ mask,
        const float* __restrict__ Xv, float* __restrict__ alphaU,
        float* __restrict__ Spart, float* __restrict__ Zpart,
        float* __restrict__ esumP) {
    // bijective XCD swizzle: 4096 = 8*512; the 4 jc blocks of a row adjacent.
    int v = ((blockIdx.x & 7) << 9) | (blockIdx.x >> 3);
    int bi = v >> 2, jc = v & 3;
    int b = bi >> 8, i = bi & 255;
    int t = threadIdx.x;
    int g = t >> 6, jl = t & 63;         // wave, lane (= local j / r)
    int j0 = jc * 64;
    int h0 = g * 2, h1 = g * 2 + 1;      // wave g owns heads 2g, 2g+1

    __shared__ __align__(16) float linksh[64 * 68];  // [j][r], pad 68
    __shared__ __align__(16) float Tsh[8 * 68];
    __shared__ __align__(16) float expsh[8 * 66];
    __shared__ __align__(16) float4 zsh[4 * 64];

    {
        const float4* lp4 = (const float4*)(link + ((size_t)bi * 256 + j0) * 64);
#pragma unroll
        for (int k = 0; k < 4; ++k) {
            int m = t + k * 256;
            int j = m >> 4, rq = m & 15;
            *(float4*)(linksh + j * 68 + rq * 4) = lp4[m];
        }
    }
    for (int m = t; m < 512; m += 256)
        Tsh[(m >> 6) * 68 + (m & 63)] = Tg[(size_t)bi * 512 + m];
    float qv0 = qk[((size_t)(b * 8 + h0) * 256 + i) * 256 + j0 + jl];
    float qv1 = qk[((size_t)(b * 8 + h1) * 256 + i) * 256 + j0 + jl];
    int mv = mask[((size_t)(b * 256 + i)) * 256 + j0 + jl];
    __syncthreads();                                             // B1

    // bias + exp (thread: j = j0+jl, heads h0,h1)
    float s0 = 0.f, s1 = 0.f;
    {
        const float4* lr = (const float4*)(linksh + jl * 68);
        const float4* t0 = (const float4*)(Tsh + h0 * 68);
        const float4* t1 = (const float4*)(Tsh + h1 * 68);
#pragma unroll
        for (int rq = 0; rq < 16; ++rq) {
            float4 lv = lr[rq];
            float4 a0 = t0[rq], a1 = t1[rq];
            s0 += lv.x * a0.x + lv.y * a0.y + lv.z * a0.z + lv.w * a0.w;
            s1 += lv.x * a1.x + lv.y * a1.y + lv.z * a1.z + lv.w * a1.w;
        }
    }
    s0 = (qv0 + s0) * SCALE_;
    s1 = (qv1 + s1) * SCALE_;
    if (mv == 0) { s0 = -1e9f; s1 = -1e9f; }
    float e0 = __expf(s0), e1 = __expf(s1);
    expsh[h0 * 66 + jl] = e0;
    expsh[h1 * 66 + jl] = e1;
    alphaU[((size_t)(b * 8 + h0) * 256 + i) * 256 + j0 + jl] = e0;
    alphaU[((size_t)(b * 8 + h1) * 256 + i) * 256 + j0 + jl] = e1;
    {   // per-chunk esums (wave-local shfl)
        float v0 = e0, v1 = e1;
        for (int off = 32; off > 0; off >>= 1) {
            v0 += __shfl_xor(v0, off);
            v1 += __shfl_xor(v1, off);
        }
        if (jl == 0) {
            esumP[((size_t)bi * 4 + jc) * 8 + h0] = v0;
            esumP[((size_t)bi * 4 + jc) * 8 + h1] = v1;
        }
    }
    __syncthreads();                                             // B2 (expsh)

    // S partials from LDS tile: lane = r, heads h0,h1 (wave-local exp rows)
    {
        float acc0 = 0.f, acc1 = 0.f;
        const float* ls = linksh + jl;
        const float* e0p = expsh + h0 * 66;
        const float* e1p = expsh + h1 * 66;
#pragma unroll 8
        for (int j = 0; j < 64; ++j) {
            float lv = ls[j * 68];
            acc0 += e0p[j] * lv;
            acc1 += e1p[j] * lv;
        }
        float* sp = Spart + ((size_t)bi * 4 + jc) * 512;
        sp[h0 * 64 + jl] = acc0;
        sp[h1 * 64 + jl] = acc1;
    }

    // Z partials: wave g owns j-quarter [16g,16g+16); slot o -> (h,dv4), f4
    {
        int o = jl;
        int h = o >> 3, dv4 = o & 7;
        const float4* xv4 = (const float4*)Xv +
            (((size_t)(b * 8 + h)) * 256 + j0 + g * 16) * 8 + dv4;
        const float* ep = expsh + h * 66 + g * 16;
        float4 z = make_float4(0.f, 0.f, 0.f, 0.f);
#pragma unroll
        for (int j = 0; j < 16; ++j) {
            float a = ep[j];
            float4 x = xv4[j * 8];
            z.x += a * x.x; z.y += a * x.y; z.z += a * x.z; z.w += a * x.w;
        }
        zsh[g * 64 + o] = z;
    }
    __syncthreads();                                             // B3
    if (t < 64) {
        float4 z0 = zsh[t], z1 = zsh[64 + t], z2 = zsh[128 + t], z3 = zsh[192 + t];
        float4 z = make_float4(z0.x + z1.x + z2.x + z3.x,
                               z0.y + z1.y + z2.y + z3.y,
                               z0.z + z1.z + z2.z + z3.z,
                               z0.w + z1.w + z2.w + z3.w);
        *(float4*)(Zpart + ((size_t)bi * 4 + jc) * 256 + t * 4) = z;
    }
}

// ---------------------------------------------------------------------------
// K4: finalize + output, 1 row per block, grid = 1024, XCD-swizzled to match
// expsz chunk placement (row r's partials were written on XCD r>>7 -> L2-hot
// re-reads). Halves the per-block serial chain vs the 2-row version and
// doubles block parallelism; LDS ~3.5 KB.
__global__ __launch_bounds__(256) void finout_kernel(
        const float* __restrict__ Spart, const float* __restrict__ Zpart,
        const float* __restrict__ esumP, const float* __restrict__ Ev,
        const float* __restrict__ Wo, const float* __restrict__ q,
        const float* __restrict__ gamma, const float* __restrict__ beta,
        float* __restrict__ alpha, float* __restrict__ out) {
    // bijective XCD swizzle: 1024 = 8*128; XCD k owns rows [128k, 128k+128)
    int row = ((blockIdx.x & 7) << 7) | (blockIdx.x >> 3);
    int b = row >> 8, i = row & 255;
    int t = threadIdx.x;
    int lane = t & 63, wv = t >> 6;
    __shared__ __align__(16) float Ssh[8 * 68];
    __shared__ __align__(16) float zsh[256];
    __shared__ float invsh[8];
    __shared__ float redsh[16];

    if (t < 8) {
        float es = esumP[((size_t)row * 4 + 0) * 8 + t] +
                   esumP[((size_t)row * 4 + 1) * 8 + t] +
                   esumP[((size_t)row * 4 + 2) * 8 + t] +
                   esumP[((size_t)row * 4 + 3) * 8 + t];
        invsh[t] = 1.f / es;
    }
    for (int m = t; m < 512; m += 256) {
        float sv = Spart[((size_t)row * 4 + 0) * 512 + m] +
                   Spart[((size_t)row * 4 + 1) * 512 + m] +
                   Spart[((size_t)row * 4 + 2) * 512 + m] +
                   Spart[((size_t)row * 4 + 3) * 512 + m];
        Ssh[(m >> 6) * 68 + (m & 63)] = sv;
    }
    __syncthreads();
#pragma unroll
    for (int k = 0; k < 8; ++k) {    // normalize alpha row (L2-hot, same XCD)
        size_t off = ((size_t)(b * 8 + k) * 256 + i) * 256 + t;
        alpha[off] *= invsh[k];
    }
    {
        int h = t >> 5, dv = t & 31;
        float zq = Zpart[((size_t)row * 4 + 0) * 256 + t] +
                   Zpart[((size_t)row * 4 + 1) * 256 + t] +
                   Zpart[((size_t)row * 4 + 2) * 256 + t] +
                   Zpart[((size_t)row * 4 + 3) * 256 + t];
        float acc = 0.f;
        const float* sp = Ssh + h * 68;
        const float* evp = Ev + h * 32 + dv;
#pragma unroll 4
        for (int r = 0; r < 64; ++r) acc += sp[r] * evp[(size_t)r * 256];
        zsh[t] = (zq + acc) * invsh[h];
    }
    __syncthreads();

    // ---- out = LN(Z @ Wo + q) ----
    float a = q[(size_t)row * 256 + t];
    {
        const float4* z4 = (const float4*)zsh;
        const float* wp = Wo + t;
#pragma unroll 4
        for (int d4 = 0; d4 < 64; ++d4) {
            float4 zz = z4[d4];
            a += zz.x * wp[(d4 * 4 + 0) * 256] + zz.y * wp[(d4 * 4 + 1) * 256] +
                 zz.z * wp[(d4 * 4 + 2) * 256] + zz.w * wp[(d4 * 4 + 3) * 256];
        }
    }
    {
        float v = a, v2 = a * a;
        for (int off = 32; off > 0; off >>= 1) {
            v += __shfl_xor(v, off);
            v2 += __shfl_xor(v2, off);
        }
        if (lane == 0) { redsh[wv] = v; redsh[8 + wv] = v2; }
    }
    __syncthreads();
    {
        float sum = redsh[0] + redsh[1] + redsh[2] + redsh[3];
        float sum2 = redsh[8] + redsh[9] + redsh[10] + redsh[11];
        float mu = sum * (1.f / 256.f);
        float var = sum2 * (1.f / 256.f) - mu * mu;
        out[(size_t)row * 256 + t] = (a - mu) * rsqrtf(var + EPS_) * gamma[t] + beta[t];
    }
}

// ---------------------------------------------------------------------------
extern "C" void kernel_launch(void* const* d_in, const int* in_sizes, int n_in,
                              void* d_out, int out_size, void* d_ws, size_t ws_size,
                              hipStream_t stream) {
    const float* q     = (const float*)d_in[0];
    const int*   mask  = (const int*)d_in[3];
    const float* link  = (const float*)d_in[4];
    const float* Wq    = (const float*)d_in[5];
    const float* Wk    = (const float*)d_in[6];
    const float* Wr    = (const float*)d_in[7];
    const float* Wv    = (const float*)d_in[8];
    const float* Wvv   = (const float*)d_in[9];
    const float* relE  = (const float*)d_in[10];
    const float* Wo    = (const float*)d_in[11];
    const float* gamma = (const float*)d_in[12];
    const float* beta  = (const float*)d_in[13];

    float* out   = (float*)d_out;
    float* alpha = out + B_ * N_ * D_;      // second output [B,H,N,N]

    float* ws = (float*)d_ws;
    float* Ek    = ws;                  // 16384
    float* Ev    = Ek + 16384;          // 16384
    float* Xq    = Ev + 16384;          // 262144
    float* Xk    = Xq + 262144;         // 262144
    float* Xv    = Xk + 262144;         // 262144
    float* T     = Xv + 262144;         // 524288
    float* qkbuf = T + 524288;          // 2097152
    float* Spart = qkbuf + 2097152;     // 2097152
    float* Zpart = Spart + 2097152;     // 1048576
    float* esumP = Zpart + 1048576;     // 32768   (total ~26 MB)

    projekev_kernel<<<200, 256, 0, stream>>>(q, Wq, Wk, Wv, relE, Wr, Wvv,
                                             Xq, Xk, Xv, Ek, Ev);
    qkT_kernel<<<640, 256, 0, stream>>>(Xq, Xk, Ek, qkbuf, T);
    expsz_kernel<<<4096, 256, 0, stream>>>(link, T, qkbuf, mask, Xv,
                                           alpha, Spart, Zpart, esumP);
    finout_kernel<<<1024, 256, 0, stream>>>(Spart, Zpart, esumP, Ev, Wo, q,
                                            gamma, beta, alpha, out);
}